// Round 2
// baseline (551.017 us; speedup 1.0000x reference)
//
#include <hip/hip_runtime.h>

// Problem constants
#define NROWS 8192
#define DDIM  512
#define MEXP  2048
#define BDIM  4
#define KTOP  8
#define EBLK  512          // energy kernel blocks (16 waves each, 1 row/wave)
#define SLICES 16          // second-stage reduce slices (512/32)

typedef unsigned long long ull;

// d_out layout (floats): h_sparse [0,262144), idx [262144,327680), 7 scalars at 327680
#define OUT_IDX     262144
#define OUT_SCAL    327680

// d_ws layout (bytes) — no global atomics; all partials plain-stored
#define WS_VT_OFF    0u                       // 16 MiB: Vt[m][d] float4 (b-dim)
#define WS_ESP_OFF   16777216u                // 512*2048 f32 = 4 MiB
#define WS_CNTP_OFF  20971520u                // 512*2048 u32 = 4 MiB
#define WS_CAP_OFF   25165824u                // 512 f32
#define WS_LRLH_OFF  25167872u                // 8192 float2 = 64 KiB
#define WS_ES2_OFF   25233408u                // 16*2048 f32 = 128 KiB
#define WS_CNT2_OFF  25364480u                // 16*2048 u32 = 128 KiB

// ---------------------------------------------------------------------------
// Kernel 1: ONE ROW PER WAVE energy + top-8.
// Round-1 post-mortem: 1024 waves total = 1 wave/SIMD (Occupancy 11.5%) made
// the kernel latency-bound at 722 GB/s regardless of staging strategy. Fix is
// TLP: 8192 waves (512 blocks x 16 waves), 1 row each -> 4 waves/SIMD
// resident (launch_bounds caps VGPR at 128). Aggregate in-flight loads then
// oversubscribe HBM and the kernel runs at the BW roofline.
// Per-element math (energy expression, insert chain, argmax, gather) is
// unchanged from the passing kernel.
// ---------------------------------------------------------------------------
__global__ __launch_bounds__(1024, 4) void energy_topk_kernel(
    const float* __restrict__ h_all, float* __restrict__ out,
    float* __restrict__ esum_part, unsigned int* __restrict__ cnt_part,
    float* __restrict__ cap_part)
{
    __shared__ float s_es[MEXP];          // 8 KB
    __shared__ unsigned int s_cnt[MEXP];  // 8 KB
    __shared__ float s_cap[16];

    const int t    = threadIdx.x;
    const int lane = t & 63;
    const int wid  = t >> 6;              // 0..15

    for (int j = t; j < MEXP; j += 1024) { s_es[j] = 0.f; s_cnt[j] = 0u; }
    __syncthreads();

    const int n = blockIdx.x * 16 + wid;  // 512*16 = 8192 rows, 1 per wave
    const float4* grow = (const float4*)(h_all + (size_t)n * (MEXP * BDIM));

    float esum[32];
    ull k[8];
#pragma unroll
    for (int j = 0; j < 8; ++j) k[j] = 0ull;
    float capw = 0.f;

#pragma unroll
    for (int i = 0; i < 32; ++i) {
        const int m = lane + 64 * i;
        const float4 h = grow[m];         // coalesced global_load_dwordx4
        // bit-exact numpy f32 sequential sum (no FMA contraction)
        float e = __fadd_rn(__fadd_rn(__fadd_rn(__fmul_rn(h.x, h.x),
                                                __fmul_rn(h.y, h.y)),
                                      __fmul_rn(h.z, h.z)),
                            __fmul_rn(h.w, h.w));
        esum[i] = e;
        ull key = ((ull)__float_as_uint(e) << 32) |
                  (ull)(0xFFFFFFFFu - (unsigned)m);
        // branchless sorted insert (descending); ties -> lower index
#pragma unroll
        for (int j = 0; j < 8; ++j) {
            const ull mx = (key > k[j]) ? key : k[j];
            const ull mn = (key > k[j]) ? k[j] : key;
            k[j] = mx;
            key  = mn;
        }
    }

    // 8 rounds of wave-wide argmax over k[0] (keys unique)
    int mym = 0;
#pragma unroll
    for (int round = 0; round < 8; ++round) {
        ull w = k[0];
#pragma unroll
        for (int off = 1; off < 64; off <<= 1) {
            const ull o = __shfl_xor(w, off, 64);
            w = (o > w) ? o : w;
        }
        const int m = (int)(0xFFFFFFFFu - (unsigned)(w & 0xFFFFFFFFull));
        if (lane == round) mym = m;
        if (lane == 0) capw += __uint_as_float((unsigned)(w >> 32));
        const bool own = (k[0] == w);
#pragma unroll
        for (int j = 0; j < 7; ++j) k[j] = own ? k[j + 1] : k[j];
        if (own) k[7] = 0ull;
    }

    if (lane < KTOP) {
        const float4 hv = grow[mym];                       // L2-hot gather
        ((float4*)out)[(size_t)n * KTOP + lane] = hv;      // h_sparse
        out[OUT_IDX + (size_t)n * KTOP + lane] = (float)mym;
        atomicAdd(&s_cnt[mym], 1u);                        // LDS atomic
    }

    // block-level reduce: per-lane regs -> LDS (distinct addr per lane)
#pragma unroll
    for (int j = 0; j < 32; ++j)
        atomicAdd(&s_es[lane + 64 * j], esum[j]);          // ds_add_f32
    if (lane == 0) s_cap[wid] = capw;
    __syncthreads();

    // flush per-block partials with plain coalesced stores
    float*        ep = esum_part + (size_t)blockIdx.x * MEXP;
    unsigned int* cp = cnt_part  + (size_t)blockIdx.x * MEXP;
    for (int j = t; j < MEXP; j += 1024) { ep[j] = s_es[j]; cp[j] = s_cnt[j]; }
    if (t == 0) {
        float c = 0.f;
#pragma unroll
        for (int w2 = 0; w2 < 16; ++w2) c += s_cap[w2];
        cap_part[blockIdx.x] = c;
    }
}

// ---------------------------------------------------------------------------
// Kernel 2: transpose V (D,M,B) -> Vt (M,D,B), float4 elements over b
// ---------------------------------------------------------------------------
__global__ __launch_bounds__(256) void transpose_v_kernel(
    const float4* __restrict__ V, float4* __restrict__ Vt)
{
    __shared__ float4 tile[32][33];
    const int bx = blockIdx.x;       // m tile: 0..63
    const int by = blockIdx.y;       // d tile: 0..15
    const int tx = threadIdx.x & 31;
    const int ty = threadIdx.x >> 5; // 0..7

#pragma unroll
    for (int i = 0; i < 4; ++i) {
        const int d = by * 32 + ty + i * 8;
        const int m = bx * 32 + tx;
        tile[ty + i * 8][tx] = V[(size_t)d * MEXP + m];
    }
    __syncthreads();
#pragma unroll
    for (int i = 0; i < 4; ++i) {
        const int m = bx * 32 + ty + i * 8;
        const int d = by * 32 + tx;
        Vt[(size_t)m * DDIM + d] = tile[tx][ty + i * 8];
    }
}

// ---------------------------------------------------------------------------
// Kernel 3: x_hat per row; per-block (lr,lh) stored to ws — ZERO atomics
// ---------------------------------------------------------------------------
__global__ __launch_bounds__(256) void recon_kernel(
    const float* __restrict__ x_flat, const float* __restrict__ out_ro,
    const float4* __restrict__ Vt, float2* __restrict__ lrlh)
{
    __shared__ float4 s_h[KTOP];
    __shared__ int    s_m[KTOP];
    __shared__ float  s_lr[4], s_lh[4];

    const int n    = blockIdx.x;
    const int t    = threadIdx.x;
    const int lane = t & 63;
    const int wid  = t >> 6;

    if (t < KTOP) {
        s_m[t] = (int)out_ro[OUT_IDX + (size_t)n * KTOP + t];
        s_h[t] = ((const float4*)out_ro)[(size_t)n * KTOP + t];
    }
    __syncthreads();

    float4 v0[KTOP], v1[KTOP];
#pragma unroll
    for (int k = 0; k < KTOP; ++k) {
        const size_t o = (size_t)s_m[k] * DDIM;
        v0[k] = Vt[o + t];          // lanes -> consecutive float4: coalesced
        v1[k] = Vt[o + t + 256];
    }
    const float x0 = x_flat[(size_t)n * DDIM + t];
    const float x1 = x_flat[(size_t)n * DDIM + t + 256];

    float xh0 = 0.f, xh1 = 0.f;
#pragma unroll
    for (int k = 0; k < KTOP; ++k) {
        const float4 hv = s_h[k];
        xh0 += v0[k].x * hv.x + v0[k].y * hv.y + v0[k].z * hv.z + v0[k].w * hv.w;
        xh1 += v1[k].x * hv.x + v1[k].y * hv.y + v1[k].z * hv.z + v1[k].w * hv.w;
    }

    const float r0 = x0 - xh0, r1 = x1 - xh1;
    float lr = r0 * r0 + r1 * r1;
    float lh = xh0 * xh0 + xh1 * xh1;

#pragma unroll
    for (int off = 32; off > 0; off >>= 1) {
        lr += __shfl_down(lr, off, 64);
        lh += __shfl_down(lh, off, 64);
    }
    if (lane == 0) { s_lr[wid] = lr; s_lh[wid] = lh; }
    __syncthreads();
    if (t == 0) {
        lrlh[n] = make_float2(s_lr[0] + s_lr[1] + s_lr[2] + s_lr[3],
                              s_lh[0] + s_lh[1] + s_lh[2] + s_lh[3]);
    }
}

// ---------------------------------------------------------------------------
// Kernel 4: stage-1 reduce of per-block expert partials: 512 -> 16 slices.
// grid (8, 16): each thread sums 32 partials (coalesced across lanes).
// ---------------------------------------------------------------------------
__global__ __launch_bounds__(256) void reduce_expert_kernel(
    const float* __restrict__ esum_part, const unsigned int* __restrict__ cnt_part,
    float* __restrict__ es2, unsigned int* __restrict__ cnt2)
{
    const int e = blockIdx.x * 256 + threadIdx.x;   // 8 blocks -> 2048
    const int s = blockIdx.y;                       // 16 slices
    float sum = 0.f;
    unsigned int c = 0u;
#pragma unroll
    for (int b = 0; b < 32; ++b) {
        const size_t row = (size_t)(s * 32 + b);
        sum += esum_part[row * MEXP + e];           // coalesced across lanes
        c   += cnt_part [row * MEXP + e];
    }
    es2 [(size_t)s * MEXP + e] = sum;
    cnt2[(size_t)s * MEXP + e] = c;
}

// ---------------------------------------------------------------------------
// Kernel 5: finalize scalars
// ---------------------------------------------------------------------------
__device__ __forceinline__ double block_reduce_d(double v, double* s4,
                                                 int lane, int wid)
{
#pragma unroll
    for (int off = 32; off > 0; off >>= 1) v += __shfl_down(v, off, 64);
    if (lane == 0) s4[wid] = v;
    __syncthreads();
    const double r = s4[0] + s4[1] + s4[2] + s4[3];
    __syncthreads();
    return r;
}

__global__ __launch_bounds__(256) void finalize_kernel(
    const float* __restrict__ es2, const unsigned int* __restrict__ cnt2,
    const float* __restrict__ cap_part, const float2* __restrict__ lrlh,
    float* __restrict__ out)
{
    __shared__ double s4[4];
    const int t = threadIdx.x, lane = t & 63, wid = t >> 6;

    double avg[8];
    unsigned int cnt[8];
    double tot = 0.0;
#pragma unroll
    for (int j = 0; j < 8; ++j) {
        const int e = t + 256 * j;
        double sacc = 0.0;
        unsigned int c = 0u;
#pragma unroll
        for (int s = 0; s < SLICES; ++s) {
            sacc += (double)es2[(size_t)s * MEXP + e];
            c    += cnt2[(size_t)s * MEXP + e];
        }
        avg[j] = sacc / (double)NROWS;
        cnt[j] = c;
        tot += avg[j];
    }
    double denom = block_reduce_d(tot, s4, lane, wid);
    denom = (denom > 1e-8) ? denom : 1e-8;

    double entl = 0.0;
#pragma unroll
    for (int j = 0; j < 8; ++j) {
        double p = avg[j] / denom;
        p = (p > 1e-8) ? p : 1e-8;
        entl -= p * log(p);
    }
    const double entropy = block_reduce_d(entl, s4, lane, wid) / log(2048.0);

    double lowl = 0.0, deadl = 0.0;
    const float expected = (float)KTOP / (float)MEXP * (float)NROWS; // 32
#pragma unroll
    for (int j = 0; j < 8; ++j) {
        const float c = (float)cnt[j];
        if (c <= 0.1f * expected)  lowl  += 1.0;
        if (c <= 0.01f * expected) deadl += 1.0;
    }
    const double low  = block_reduce_d(lowl, s4, lane, wid);
    const double dead = block_reduce_d(deadl, s4, lane, wid);

    // scalar partial sums (all plain loads; tiny). cap_part has 512 entries.
    double capl = (double)cap_part[t] + (double)cap_part[t + 256];
    const double capsum = block_reduce_d(capl, s4, lane, wid);

    double lrl = 0.0, lhl = 0.0;
    for (int i = t; i < NROWS; i += 256) {
        const float2 v = lrlh[i];
        lrl += (double)v.x;
        lhl += (double)v.y;
    }
    const double lrsum = block_reduce_d(lrl, s4, lane, wid);
    const double lhsum = block_reduce_d(lhl, s4, lane, wid);

    if (t == 0) {
        const double captured = capsum / (double)NROWS;
        const double uncap    = lrsum  / (double)NROWS;
        const double recon    = lhsum  / (double)NROWS;
        out[OUT_SCAL + 0] = (float)captured;
        out[OUT_SCAL + 1] = (float)recon;
        out[OUT_SCAL + 2] = (float)uncap;
        out[OUT_SCAL + 3] = (float)entropy;
        out[OUT_SCAL + 4] = (float)(uncap + 0.01 * (1.0 - entropy));
        out[OUT_SCAL + 5] = (float)low;
        out[OUT_SCAL + 6] = (float)dead;
    }
}

// ---------------------------------------------------------------------------
extern "C" void kernel_launch(void* const* d_in, const int* in_sizes, int n_in,
                              void* d_out, int out_size, void* d_ws, size_t ws_size,
                              hipStream_t stream)
{
    const float* x = (const float*)d_in[0];
    const float* h = (const float*)d_in[1];
    const float* V = (const float*)d_in[2];
    float* out = (float*)d_out;
    char*  ws  = (char*)d_ws;

    float4*       Vt         = (float4*)(ws + WS_VT_OFF);
    float*        esum_part  = (float*)(ws + WS_ESP_OFF);
    unsigned int* cnt_part   = (unsigned int*)(ws + WS_CNTP_OFF);
    float*        cap_part   = (float*)(ws + WS_CAP_OFF);
    float2*       lrlh       = (float2*)(ws + WS_LRLH_OFF);
    float*        es2        = (float*)(ws + WS_ES2_OFF);
    unsigned int* cnt2       = (unsigned int*)(ws + WS_CNT2_OFF);

    // no memset needed: every partial slot is fully written each call

    transpose_v_kernel<<<dim3(64, 16), 256, 0, stream>>>((const float4*)V, Vt);
    energy_topk_kernel<<<EBLK, 1024, 0, stream>>>(h, out, esum_part, cnt_part,
                                                  cap_part);
    recon_kernel<<<NROWS, 256, 0, stream>>>(x, out, Vt, lrlh);
    reduce_expert_kernel<<<dim3(8, SLICES), 256, 0, stream>>>(esum_part, cnt_part,
                                                              es2, cnt2);
    finalize_kernel<<<1, 256, 0, stream>>>(es2, cnt2, cap_part, lrlh, out);
}

// Round 4
// 512.656 us; speedup vs baseline: 1.0748x; 1.0748x over previous
//
#include <hip/hip_runtime.h>

// Problem constants
#define NROWS 8192
#define DDIM  512
#define MEXP  2048
#define BDIM  4
#define KTOP  8
#define EBLK  512          // energy kernel blocks (16 waves each, 1 row/wave)
#define SLICES 16          // second-stage reduce slices (512/32)

typedef unsigned long long ull;

// d_out layout (floats): h_sparse [0,262144), idx [262144,327680), 7 scalars at 327680
#define OUT_IDX     262144
#define OUT_SCAL    327680

// d_ws layout (bytes) — no global atomics; all partials plain-stored
#define WS_VT_OFF    0u                       // 16 MiB: Vt[m][d] float4 (b-dim)
#define WS_ESP_OFF   16777216u                // 512*2048 f32 = 4 MiB
#define WS_CNTP_OFF  20971520u                // 512*2048 u32 = 4 MiB
#define WS_CAP_OFF   25165824u                // 512 f32
#define WS_LRLH_OFF  25167872u                // 8192 float2 = 64 KiB
#define WS_ES2_OFF   25233408u                // 16*2048 f32 = 128 KiB
#define WS_CNT2_OFF  25364480u                // 16*2048 u32 = 128 KiB

// ---------------------------------------------------------------------------
// Kernel 1: one row per wave, REGISTER DOUBLE-BUFFERED streaming.
// Round-2 post-mortem: occupancy 45% but still 183 us / 0.8 TB/s. VGPR=52
// showed the compiler had no registers to pipeline loads (esum[32]+k[8] live
// across the loop) -> ~1 load in flight per wave -> latency chain, not BW.
// Fix: (a) drop esum[32] (immediate ds_add_f32 per element — identical addend
// set, order already nondeterministic), (b) explicit 2-deep batch pipeline:
// 4 batches of 8 float4 (8 KB), load batch b+1 while inserting batch b.
// Steady-state in-flight = 8 KB/wave x 4096 waves = 32 MB >> latency-BW
// product. (c) rotate batch start phase by wave id (bit-exact: top-8 insert
// and capw extraction are order-invariant) to avoid 32KB-stride channel
// camping across lockstep waves.
// ---------------------------------------------------------------------------
__device__ __forceinline__ void load_batch(const float4* __restrict__ grow,
                                           int lane, int ib, float4 H[8])
{
#pragma unroll
    for (int j = 0; j < 8; ++j)
        H[j] = grow[lane + 64 * (ib * 8 + j)];
}

__device__ __forceinline__ void proc_batch(const float4 H[8], int lane, int ib,
                                           ull k[8], float* s_es)
{
#pragma unroll
    for (int j = 0; j < 8; ++j) {
        const int m = lane + 64 * (ib * 8 + j);
        const float4 h = H[j];
        // bit-exact numpy f32 sequential sum (no FMA contraction)
        const float e = __fadd_rn(__fadd_rn(__fadd_rn(__fmul_rn(h.x, h.x),
                                                      __fmul_rn(h.y, h.y)),
                                            __fmul_rn(h.z, h.z)),
                                  __fmul_rn(h.w, h.w));
        atomicAdd(&s_es[m], e);               // ds_add_f32, distinct addr/lane
        ull key = ((ull)__float_as_uint(e) << 32) |
                  (ull)(0xFFFFFFFFu - (unsigned)m);
        // branchless sorted insert (descending); ties -> lower index.
        // Final k[] = top-8 keys sorted desc: invariant to insertion order.
#pragma unroll
        for (int q = 0; q < 8; ++q) {
            const ull mx = (key > k[q]) ? key : k[q];
            const ull mn = (key > k[q]) ? k[q] : key;
            k[q] = mx;
            key  = mn;
        }
    }
}

__global__ __launch_bounds__(1024, 4) void energy_topk_kernel(
    const float* __restrict__ h_all, float* __restrict__ out,
    float* __restrict__ esum_part, unsigned int* __restrict__ cnt_part,
    float* __restrict__ cap_part)
{
    __shared__ float s_es[MEXP];          // 8 KB
    __shared__ unsigned int s_cnt[MEXP];  // 8 KB
    __shared__ float s_cap[16];

    const int t    = threadIdx.x;
    const int lane = t & 63;
    const int wid  = t >> 6;              // 0..15

    for (int j = t; j < MEXP; j += 1024) { s_es[j] = 0.f; s_cnt[j] = 0u; }
    __syncthreads();

    const int n = blockIdx.x * 16 + wid;  // 512*16 = 8192 rows, 1 per wave
    const float4* grow = (const float4*)(h_all + (size_t)n * (MEXP * BDIM));

    ull k[8];
#pragma unroll
    for (int j = 0; j < 8; ++j) k[j] = 0ull;
    float capw = 0.f;

    // phase-rotated batch order (4 batches x 8 KB covers the 32 KB row)
    const int i0 = (wid    ) & 3;
    const int i1 = (wid + 1) & 3;
    const int i2 = (wid + 2) & 3;
    const int i3 = (wid + 3) & 3;

    float4 hA[8], hB[8];
    load_batch(grow, lane, i0, hA);       // 8 KB in flight
    load_batch(grow, lane, i1, hB);       // 16 KB in flight
    proc_batch(hA, lane, i0, k, s_es);
    load_batch(grow, lane, i2, hA);
    proc_batch(hB, lane, i1, k, s_es);
    load_batch(grow, lane, i3, hB);
    proc_batch(hA, lane, i2, k, s_es);
    proc_batch(hB, lane, i3, k, s_es);

    // 8 rounds of wave-wide argmax over k[0] (keys unique)
    int mym = 0;
#pragma unroll
    for (int round = 0; round < 8; ++round) {
        ull w = k[0];
#pragma unroll
        for (int off = 1; off < 64; off <<= 1) {
            const ull o = __shfl_xor(w, off, 64);
            w = (o > w) ? o : w;
        }
        const int m = (int)(0xFFFFFFFFu - (unsigned)(w & 0xFFFFFFFFull));
        if (lane == round) mym = m;
        if (lane == 0) capw += __uint_as_float((unsigned)(w >> 32));
        const bool own = (k[0] == w);
#pragma unroll
        for (int j = 0; j < 7; ++j) k[j] = own ? k[j + 1] : k[j];
        if (own) k[7] = 0ull;
    }

    if (lane < KTOP) {
        const float4 hv = grow[mym];                       // L2-hot gather
        ((float4*)out)[(size_t)n * KTOP + lane] = hv;      // h_sparse
        out[OUT_IDX + (size_t)n * KTOP + lane] = (float)mym;
        atomicAdd(&s_cnt[mym], 1u);                        // LDS atomic
    }

    if (lane == 0) s_cap[wid] = capw;
    __syncthreads();

    // flush per-block partials with plain coalesced stores
    float*        ep = esum_part + (size_t)blockIdx.x * MEXP;
    unsigned int* cp = cnt_part  + (size_t)blockIdx.x * MEXP;
    for (int j = t; j < MEXP; j += 1024) { ep[j] = s_es[j]; cp[j] = s_cnt[j]; }
    if (t == 0) {
        float c = 0.f;
#pragma unroll
        for (int w2 = 0; w2 < 16; ++w2) c += s_cap[w2];
        cap_part[blockIdx.x] = c;
    }
}

// ---------------------------------------------------------------------------
// Kernel 2: transpose V (D,M,B) -> Vt (M,D,B), float4 elements over b
// ---------------------------------------------------------------------------
__global__ __launch_bounds__(256) void transpose_v_kernel(
    const float4* __restrict__ V, float4* __restrict__ Vt)
{
    __shared__ float4 tile[32][33];
    const int bx = blockIdx.x;       // m tile: 0..63
    const int by = blockIdx.y;       // d tile: 0..15
    const int tx = threadIdx.x & 31;
    const int ty = threadIdx.x >> 5; // 0..7

#pragma unroll
    for (int i = 0; i < 4; ++i) {
        const int d = by * 32 + ty + i * 8;
        const int m = bx * 32 + tx;
        tile[ty + i * 8][tx] = V[(size_t)d * MEXP + m];
    }
    __syncthreads();
#pragma unroll
    for (int i = 0; i < 4; ++i) {
        const int m = bx * 32 + ty + i * 8;
        const int d = by * 32 + tx;
        Vt[(size_t)m * DDIM + d] = tile[tx][ty + i * 8];
    }
}

// ---------------------------------------------------------------------------
// Kernel 3: x_hat per row; per-block (lr,lh) stored to ws — ZERO atomics
// ---------------------------------------------------------------------------
__global__ __launch_bounds__(256) void recon_kernel(
    const float* __restrict__ x_flat, const float* __restrict__ out_ro,
    const float4* __restrict__ Vt, float2* __restrict__ lrlh)
{
    __shared__ float4 s_h[KTOP];
    __shared__ int    s_m[KTOP];
    __shared__ float  s_lr[4], s_lh[4];

    const int n    = blockIdx.x;
    const int t    = threadIdx.x;
    const int lane = t & 63;
    const int wid  = t >> 6;

    if (t < KTOP) {
        s_m[t] = (int)out_ro[OUT_IDX + (size_t)n * KTOP + t];
        s_h[t] = ((const float4*)out_ro)[(size_t)n * KTOP + t];
    }
    __syncthreads();

    float4 v0[KTOP], v1[KTOP];
#pragma unroll
    for (int k = 0; k < KTOP; ++k) {
        const size_t o = (size_t)s_m[k] * DDIM;
        v0[k] = Vt[o + t];          // lanes -> consecutive float4: coalesced
        v1[k] = Vt[o + t + 256];
    }
    const float x0 = x_flat[(size_t)n * DDIM + t];
    const float x1 = x_flat[(size_t)n * DDIM + t + 256];

    float xh0 = 0.f, xh1 = 0.f;
#pragma unroll
    for (int k = 0; k < KTOP; ++k) {
        const float4 hv = s_h[k];
        xh0 += v0[k].x * hv.x + v0[k].y * hv.y + v0[k].z * hv.z + v0[k].w * hv.w;
        xh1 += v1[k].x * hv.x + v1[k].y * hv.y + v1[k].z * hv.z + v1[k].w * hv.w;
    }

    const float r0 = x0 - xh0, r1 = x1 - xh1;
    float lr = r0 * r0 + r1 * r1;
    float lh = xh0 * xh0 + xh1 * xh1;

#pragma unroll
    for (int off = 32; off > 0; off >>= 1) {
        lr += __shfl_down(lr, off, 64);
        lh += __shfl_down(lh, off, 64);
    }
    if (lane == 0) { s_lr[wid] = lr; s_lh[wid] = lh; }
    __syncthreads();
    if (t == 0) {
        lrlh[n] = make_float2(s_lr[0] + s_lr[1] + s_lr[2] + s_lr[3],
                              s_lh[0] + s_lh[1] + s_lh[2] + s_lh[3]);
    }
}

// ---------------------------------------------------------------------------
// Kernel 4: stage-1 reduce of per-block expert partials: 512 -> 16 slices.
// grid (8, 16): each thread sums 32 partials (coalesced across lanes).
// ---------------------------------------------------------------------------
__global__ __launch_bounds__(256) void reduce_expert_kernel(
    const float* __restrict__ esum_part, const unsigned int* __restrict__ cnt_part,
    float* __restrict__ es2, unsigned int* __restrict__ cnt2)
{
    const int e = blockIdx.x * 256 + threadIdx.x;   // 8 blocks -> 2048
    const int s = blockIdx.y;                       // 16 slices
    float sum = 0.f;
    unsigned int c = 0u;
#pragma unroll
    for (int b = 0; b < 32; ++b) {
        const size_t row = (size_t)(s * 32 + b);
        sum += esum_part[row * MEXP + e];           // coalesced across lanes
        c   += cnt_part [row * MEXP + e];
    }
    es2 [(size_t)s * MEXP + e] = sum;
    cnt2[(size_t)s * MEXP + e] = c;
}

// ---------------------------------------------------------------------------
// Kernel 5: finalize scalars
// ---------------------------------------------------------------------------
__device__ __forceinline__ double block_reduce_d(double v, double* s4,
                                                 int lane, int wid)
{
#pragma unroll
    for (int off = 32; off > 0; off >>= 1) v += __shfl_down(v, off, 64);
    if (lane == 0) s4[wid] = v;
    __syncthreads();
    const double r = s4[0] + s4[1] + s4[2] + s4[3];
    __syncthreads();
    return r;
}

__global__ __launch_bounds__(256) void finalize_kernel(
    const float* __restrict__ es2, const unsigned int* __restrict__ cnt2,
    const float* __restrict__ cap_part, const float2* __restrict__ lrlh,
    float* __restrict__ out)
{
    __shared__ double s4[4];
    const int t = threadIdx.x, lane = t & 63, wid = t >> 6;

    double avg[8];
    unsigned int cnt[8];
    double tot = 0.0;
#pragma unroll
    for (int j = 0; j < 8; ++j) {
        const int e = t + 256 * j;
        double sacc = 0.0;
        unsigned int c = 0u;
#pragma unroll
        for (int s = 0; s < SLICES; ++s) {
            sacc += (double)es2[(size_t)s * MEXP + e];
            c    += cnt2[(size_t)s * MEXP + e];
        }
        avg[j] = sacc / (double)NROWS;
        cnt[j] = c;
        tot += avg[j];
    }
    double denom = block_reduce_d(tot, s4, lane, wid);
    denom = (denom > 1e-8) ? denom : 1e-8;

    double entl = 0.0;
#pragma unroll
    for (int j = 0; j < 8; ++j) {
        double p = avg[j] / denom;
        p = (p > 1e-8) ? p : 1e-8;
        entl -= p * log(p);
    }
    const double entropy = block_reduce_d(entl, s4, lane, wid) / log(2048.0);

    double lowl = 0.0, deadl = 0.0;
    const float expected = (float)KTOP / (float)MEXP * (float)NROWS; // 32
#pragma unroll
    for (int j = 0; j < 8; ++j) {
        const float c = (float)cnt[j];
        if (c <= 0.1f * expected)  lowl  += 1.0;
        if (c <= 0.01f * expected) deadl += 1.0;
    }
    const double low  = block_reduce_d(lowl, s4, lane, wid);
    const double dead = block_reduce_d(deadl, s4, lane, wid);

    // scalar partial sums (all plain loads; tiny). cap_part has 512 entries.
    double capl = (double)cap_part[t] + (double)cap_part[t + 256];
    const double capsum = block_reduce_d(capl, s4, lane, wid);

    double lrl = 0.0, lhl = 0.0;
    for (int i = t; i < NROWS; i += 256) {
        const float2 v = lrlh[i];
        lrl += (double)v.x;
        lhl += (double)v.y;
    }
    const double lrsum = block_reduce_d(lrl, s4, lane, wid);
    const double lhsum = block_reduce_d(lhl, s4, lane, wid);

    if (t == 0) {
        const double captured = capsum / (double)NROWS;
        const double uncap    = lrsum  / (double)NROWS;
        const double recon    = lhsum  / (double)NROWS;
        out[OUT_SCAL + 0] = (float)captured;
        out[OUT_SCAL + 1] = (float)recon;
        out[OUT_SCAL + 2] = (float)uncap;
        out[OUT_SCAL + 3] = (float)entropy;
        out[OUT_SCAL + 4] = (float)(uncap + 0.01 * (1.0 - entropy));
        out[OUT_SCAL + 5] = (float)low;
        out[OUT_SCAL + 6] = (float)dead;
    }
}

// ---------------------------------------------------------------------------
extern "C" void kernel_launch(void* const* d_in, const int* in_sizes, int n_in,
                              void* d_out, int out_size, void* d_ws, size_t ws_size,
                              hipStream_t stream)
{
    const float* x = (const float*)d_in[0];
    const float* h = (const float*)d_in[1];
    const float* V = (const float*)d_in[2];
    float* out = (float*)d_out;
    char*  ws  = (char*)d_ws;

    float4*       Vt         = (float4*)(ws + WS_VT_OFF);
    float*        esum_part  = (float*)(ws + WS_ESP_OFF);
    unsigned int* cnt_part   = (unsigned int*)(ws + WS_CNTP_OFF);
    float*        cap_part   = (float*)(ws + WS_CAP_OFF);
    float2*       lrlh       = (float2*)(ws + WS_LRLH_OFF);
    float*        es2        = (float*)(ws + WS_ES2_OFF);
    unsigned int* cnt2       = (unsigned int*)(ws + WS_CNT2_OFF);

    // no memset needed: every partial slot is fully written each call

    transpose_v_kernel<<<dim3(64, 16), 256, 0, stream>>>((const float4*)V, Vt);
    energy_topk_kernel<<<EBLK, 1024, 0, stream>>>(h, out, esum_part, cnt_part,
                                                  cap_part);
    recon_kernel<<<NROWS, 256, 0, stream>>>(x, out, Vt, lrlh);
    reduce_expert_kernel<<<dim3(8, SLICES), 256, 0, stream>>>(esum_part, cnt_part,
                                                              es2, cnt2);
    finalize_kernel<<<1, 256, 0, stream>>>(es2, cnt2, cap_part, lrlh, out);
}